// Round 5
// baseline (58.139 us; speedup 1.0000x reference)
//
#include <hip/hip_runtime.h>

// DifferentiableCIndexLoss:
//   mask[i,j] = (t[i] < t[j]) && (e[i]==1)
//   loss = sum sigmoid((r[j]-r[i])/SIGMA) * mask ;  count = sum mask
//   out  = loss / (count + 1e-6)
//
// R5: exact bucket-sort (2048 time buckets) of active rows (e==1) and all
// columns, as THREE small pipelined kernels (hist -> scan+bounds -> scatter)
// instead of R4's spin-fused prep (the spin serialized ~35us). Main kernel:
// block = (row-chunk of 256, 8 strided j-pages); rows loaded once per block.
// Tile classes via bucket bounds: all-false skip; all-true fma+rcp+add with
// analytic count; mixed (diagonal band) exact per-pair compare.
//   sigmoid((r_j-r_i)/sigma) = 1/(1 + 2^{s_i} * 2^{-s_j}), s=r*log2e/sigma
//   clamped to +-60 (product in [2^-120,2^120], no overflow/NaN).

#define BLOCK 256
#define NB 2048
#define NBPT (NB / BLOCK)      // 8 buckets per thread in scan
#define ROWCHUNK 256
#define RC_SHIFT 8
#define MAXRC 64               // 16384/256
#define JPAGE 64
#define JP_SHIFT 6
#define MAXPG 256              // 16384/64
#define PAGES_PER_BLK 8
#define GRID_MAIN (MAXRC * (MAXPG / PAGES_PER_BLK))   // 64*32 = 2048

__device__ __forceinline__ float fast_exp2(float x) { return __builtin_amdgcn_exp2f(x); }
__device__ __forceinline__ float fast_rcp(float x)  { return __builtin_amdgcn_rcpf(x); }
__device__ __forceinline__ float clamp60(float x)   { return fminf(fmaxf(x, -60.0f), 60.0f); }
__device__ __forceinline__ int bucket_of(float tv) {
    int b = (int)(tv * (float)NB);
    return min(max(b, 0), NB - 1);
}

// ---- 1) histogram -----------------------------------------------------------
__global__ __launch_bounds__(BLOCK) void k_hist(
    const float* __restrict__ t, const int* __restrict__ ev, int B,
    int* __restrict__ histI, int* __restrict__ histJ) {
    int g = blockIdx.x * BLOCK + threadIdx.x;
    if (g < B) {
        int b = bucket_of(t[g]);
        atomicAdd(&histJ[b], 1);
        if (ev[g] == 1) atomicAdd(&histI[b], 1);
    }
}

// ---- 2) scan + chunk/page bucket bounds (single block) ----------------------
__global__ __launch_bounds__(BLOCK) void k_scan(
    const int* __restrict__ histI, const int* __restrict__ histJ,
    int* __restrict__ curI, int* __restrict__ curJ,
    int* __restrict__ rcLo, int* __restrict__ rcHi,
    int* __restrict__ jpLo, int* __restrict__ jpHi,
    int* __restrict__ nactive_g) {

    const int tid = threadIdx.x;
    __shared__ int ts[BLOCK];
    __shared__ int rcLo_s[MAXRC], rcHi_s[MAXRC];
    __shared__ int jpLo_s[MAXPG], jpHi_s[MAXPG];
    for (int i = tid; i < MAXRC; i += BLOCK) { rcLo_s[i] = 0x7fffffff; rcHi_s[i] = -1; }
    for (int i = tid; i < MAXPG; i += BLOCK) { jpLo_s[i] = 0x7fffffff; jpHi_s[i] = -1; }
    __syncthreads();

    const int b0 = tid * NBPT;
    // ---- I (active rows) ----
    {
        int cnt[NBPT], pre[NBPT], s = 0;
#pragma unroll
        for (int k = 0; k < NBPT; ++k) { int v = histI[b0 + k]; cnt[k] = v; pre[k] = s; s += v; }
        ts[tid] = s; __syncthreads();
        for (int off = 1; off < BLOCK; off <<= 1) {
            int v = (tid >= off) ? ts[tid - off] : 0;
            __syncthreads();
            ts[tid] += v;
            __syncthreads();
        }
        int excl = ts[tid] - s;
        if (tid == BLOCK - 1) *nactive_g = ts[BLOCK - 1];
#pragma unroll
        for (int k = 0; k < NBPT; ++k) {
            int o = excl + pre[k];
            curI[b0 + k] = o;
            if (cnt[k] > 0) {
                int c0 = o >> RC_SHIFT, c1 = (o + cnt[k] - 1) >> RC_SHIFT;
                for (int c = c0; c <= c1; ++c) {
                    atomicMin(&rcLo_s[c], b0 + k);
                    atomicMax(&rcHi_s[c], b0 + k);
                }
            }
        }
        __syncthreads();
    }
    // ---- J (all columns) ----
    {
        int cnt[NBPT], pre[NBPT], s = 0;
#pragma unroll
        for (int k = 0; k < NBPT; ++k) { int v = histJ[b0 + k]; cnt[k] = v; pre[k] = s; s += v; }
        ts[tid] = s; __syncthreads();
        for (int off = 1; off < BLOCK; off <<= 1) {
            int v = (tid >= off) ? ts[tid - off] : 0;
            __syncthreads();
            ts[tid] += v;
            __syncthreads();
        }
        int excl = ts[tid] - s;
#pragma unroll
        for (int k = 0; k < NBPT; ++k) {
            int o = excl + pre[k];
            curJ[b0 + k] = o;
            if (cnt[k] > 0) {
                int c0 = o >> JP_SHIFT, c1 = (o + cnt[k] - 1) >> JP_SHIFT;
                for (int c = c0; c <= c1; ++c) {
                    atomicMin(&jpLo_s[c], b0 + k);
                    atomicMax(&jpHi_s[c], b0 + k);
                }
            }
        }
        __syncthreads();
    }
    for (int i = tid; i < MAXRC; i += BLOCK) { rcLo[i] = rcLo_s[i]; rcHi[i] = rcHi_s[i]; }
    for (int i = tid; i < MAXPG; i += BLOCK) { jpLo[i] = jpLo_s[i]; jpHi[i] = jpHi_s[i]; }
}

// ---- 3) scatter into sorted arrays ------------------------------------------
__global__ __launch_bounds__(BLOCK) void k_scatter(
    const float* __restrict__ r, const float* __restrict__ t,
    const int* __restrict__ ev, int B, float kscale,
    int* __restrict__ curI, int* __restrict__ curJ,
    float2* __restrict__ sI, float2* __restrict__ sJ) {
    int g = blockIdx.x * BLOCK + threadIdx.x;
    if (g < B) {
        float tv = t[g];
        float s = clamp60(r[g] * kscale);
        int b = bucket_of(tv);
        int pj = atomicAdd(&curJ[b], 1);
        sJ[pj] = make_float2(fast_exp2(-s), tv);
        if (ev[g] == 1) {
            int pi = atomicAdd(&curI[b], 1);
            sI[pi] = make_float2(fast_exp2(s), tv);
        }
    }
}

// ---- 4) main: classified tiles ----------------------------------------------
__global__ __launch_bounds__(BLOCK) void k_main(
    const float2* __restrict__ sI, const float2* __restrict__ sJ,
    const int* __restrict__ rcLo, const int* __restrict__ rcHi,
    const int* __restrict__ jpLo, const int* __restrict__ jpHi,
    const int* __restrict__ nactive_g,
    float* __restrict__ pL, unsigned int* __restrict__ pC) {

    const int tid = threadIdx.x;
    const int rc = blockIdx.x & (MAXRC - 1);
    const int p0 = blockIdx.x >> 6;          // 0..31
    const int nactive = *nactive_g;
    const int rl = rcLo[rc], rh = rcHi[rc];

    __shared__ float2 tile[JPAGE];

    // my row (loaded once, reused for all 8 pages)
    int rr = (rc << RC_SHIFT) + tid;
    int v0 = (rr < nactive) ? 1 : 0;
    float Ei, ti;
    if (v0) { float2 f = sI[rr]; Ei = f.x; ti = f.y; }
    else    { Ei = __builtin_inff(); ti = 3.0f; }   // rcp(1+inf*F)=0 ; mask never

    float lsum = 0.0f;
    int   csum = 0;

#pragma unroll
    for (int k = 0; k < PAGES_PER_BLK; ++k) {
        int p = p0 + (k << 5);
        int jh = jpHi[p];
        if (rl > jh) continue;               // all-false (incl. empty row-chunk)
        int jl = jpLo[p];

        __syncthreads();                     // block-uniform path; safe
        if (tid < JPAGE) tile[tid] = sJ[(p << JP_SHIFT) + tid];
        __syncthreads();

        if (rh < jl) {                       // all-true: no compare, analytic cnt
            float l = 0.0f;
#pragma unroll 8
            for (int jj = 0; jj < JPAGE; ++jj)
                l += fast_rcp(__builtin_fmaf(Ei, tile[jj].x, 1.0f));
            lsum += l;
            csum += v0 << JP_SHIFT;          // v0 * 64
        } else {                             // mixed: exact per-pair compare
            float l = 0.0f; int c = 0;
#pragma unroll 4
            for (int jj = 0; jj < JPAGE; ++jj) {
                float2 q = tile[jj];
                float sg = fast_rcp(__builtin_fmaf(Ei, q.x, 1.0f));
                bool m = ti < q.y;
                l += m ? sg : 0.0f;
                c += m;
            }
            lsum += l;
            csum += c;
        }
    }

    // block reduce
#pragma unroll
    for (int off = 32; off > 0; off >>= 1) {
        lsum += __shfl_down(lsum, off);
        csum += __shfl_down(csum, off);
    }
    __shared__ float lw[BLOCK / 64];
    __shared__ int   cw[BLOCK / 64];
    int wid = tid >> 6;
    if ((tid & 63) == 0) { lw[wid] = lsum; cw[wid] = csum; }
    __syncthreads();
    if (tid == 0) {
        pL[blockIdx.x] = (lw[0] + lw[1]) + (lw[2] + lw[3]);
        pC[blockIdx.x] = (unsigned)((cw[0] + cw[1]) + (cw[2] + cw[3]));
    }
}

// ---- 5) finalize -------------------------------------------------------------
__global__ __launch_bounds__(BLOCK) void k_finalize(
    const float* __restrict__ pL, const unsigned int* __restrict__ pC,
    int n, float* __restrict__ out) {
    double l = 0.0, c = 0.0;
    for (int i = threadIdx.x; i < n; i += BLOCK) {
        l += (double)pL[i];
        c += (double)pC[i];
    }
#pragma unroll
    for (int off = 32; off > 0; off >>= 1) {
        l += __shfl_down(l, off);
        c += __shfl_down(c, off);
    }
    __shared__ double lw[BLOCK / 64], cw[BLOCK / 64];
    int wid = threadIdx.x >> 6;
    if ((threadIdx.x & 63) == 0) { lw[wid] = l; cw[wid] = c; }
    __syncthreads();
    if (threadIdx.x == 0) {
        double L = (lw[0] + lw[1]) + (lw[2] + lw[3]);
        double C = (cw[0] + cw[1]) + (cw[2] + cw[3]);
        out[0] = (float)(L / (C + 1e-6));
    }
}

extern "C" void kernel_launch(void* const* d_in, const int* in_sizes, int n_in,
                              void* d_out, int out_size, void* d_ws, size_t ws_size,
                              hipStream_t stream) {
    const float* r  = (const float*)d_in[0];
    const float* t  = (const float*)d_in[1];
    const int*   ev = (const int*)d_in[2];
    float* out = (float*)d_out;
    const int B = in_sizes[0];   // 16384

    const float SIGMA = 0.1f;
    const float LOG2E = 1.4426950408889634f;
    const float kscale = LOG2E / SIGMA;

    char* ws = (char*)d_ws;
    int* histI = (int*)(ws + 0);                  // 8 KB   (memset)
    int* histJ = (int*)(ws + 4 * NB);             // 8 KB   (memset)
    int* curI  = (int*)(ws + 8 * NB);             // 8 KB
    int* curJ  = (int*)(ws + 12 * NB);            // 8 KB
    int* rcLo  = (int*)(ws + 16 * NB);
    int* rcHi  = rcLo + MAXRC;
    int* jpLo  = rcHi + MAXRC;
    int* jpHi  = jpLo + MAXPG;
    int* nactive_g = jpHi + MAXPG;
    float2* sI = (float2*)(ws + 16 * NB + 8192);  // 128 KB
    float2* sJ = sI + B;                          // 128 KB
    float*  pL = (float*)(sJ + B);
    unsigned int* pC = (unsigned int*)(pL + GRID_MAIN);

    const int nblk = (B + BLOCK - 1) / BLOCK;     // 64

    hipMemsetAsync(ws, 0, 8 * NB, stream);        // zero both histograms
    k_hist<<<nblk, BLOCK, 0, stream>>>(t, ev, B, histI, histJ);
    k_scan<<<1, BLOCK, 0, stream>>>(histI, histJ, curI, curJ,
                                    rcLo, rcHi, jpLo, jpHi, nactive_g);
    k_scatter<<<nblk, BLOCK, 0, stream>>>(r, t, ev, B, kscale, curI, curJ, sI, sJ);
    k_main<<<GRID_MAIN, BLOCK, 0, stream>>>(sI, sJ, rcLo, rcHi, jpLo, jpHi,
                                            nactive_g, pL, pC);
    k_finalize<<<1, BLOCK, 0, stream>>>(pL, pC, GRID_MAIN, out);
}